// Round 3
// baseline (1313.668 us; speedup 1.0000x reference)
//
#include <hip/hip_runtime.h>
#include <hip/hip_bf16.h>

#define TN 24
#define HID 64

typedef __attribute__((ext_vector_type(8))) short bf16x8;
typedef __attribute__((ext_vector_type(4))) float f32x4;

__device__ __forceinline__ ushort bf16rn(float f) {
    return __builtin_bit_cast(ushort, __float2bfloat16(f));
}
__device__ __forceinline__ float bf16tof(ushort u) {
    return __uint_as_float(((uint)u) << 16);
}
__device__ __forceinline__ float sigm(float v) { return 1.0f / (1.0f + __expf(-v)); }

extern "C" __global__ void __launch_bounds__(512, 4)
traj_gru_mfma(const float* __restrict__ x, const float* __restrict__ Wloc,
              const float* __restrict__ bloc, const float* __restrict__ tt,
              const float* __restrict__ Wih, const float* __restrict__ Whh,
              const float* __restrict__ bih, const float* __restrict__ bhh,
              const float* __restrict__ Wpred, const float* __restrict__ bpred,
              float* __restrict__ out)
{
    // Static LDS: 18432 + 256 + 384 + 18432 + 18432 + 4096 = 60032 B (2 blocks/CU)
    __shared__ float gicS[TN * 192];
    __shared__ float bhnS[64];
    __shared__ float wlcS[96];
    __shared__ __align__(16) ushort Hhi[8][16][72];
    __shared__ __align__(16) ushort Hlo[8][16][72];
    __shared__ __align__(16) ushort WnF[4][64][8];

    const int tid  = threadIdx.x;
    const int lane = tid & 63;
    const int wid  = tid >> 6;       // wave 0..7
    const int er   = lane & 15;      // A-row / B-col / D-col index
    const int cp   = lane >> 4;      // k-block / D-row-block

    // ---------- setup: gic[t][g] = b_ih[g] + (g<128? b_hh[g]:0) + Wih[g][32:]·leaky(tt[t]) ----------
    for (int i = tid; i < TN * 192; i += 512) {
        int t = i / 192, g = i % 192;
        float acc = bih[g] + (g < 128 ? bhh[g] : 0.0f);
        const float* ttr = tt + t * 32;
        const float* wr  = Wih + g * 64 + 32;
        #pragma unroll
        for (int k = 0; k < 32; ++k) {
            float e = ttr[k];
            e = e > 0.0f ? e : 0.2f * e;
            acc = fmaf(wr[k], e, acc);
        }
        gicS[i] = acc;
    }
    if (tid < 64) bhnS[tid] = bhh[128 + tid];
    if (tid < 96) wlcS[tid] = (tid < 64) ? Wloc[tid] : bloc[tid - 64];

    // ---------- setup: weight fragments ----------
    // A-frag layout (mfma_f32_16x16x32_bf16): lane holds A[row=lane&15][k=8*(lane>>4)+j], j=0..7
    bf16x8 wihRZ[2][4];     // gates r,z input-part (K=32)
    bf16x8 whhF[3][4][2];   // gates r,z,n recurrent (K=64 -> 2 frags)
    {
        #pragma unroll
        for (int g = 0; g < 2; ++g)
            #pragma unroll
            for (int a = 0; a < 4; ++a) {
                int o = g * 64 + a * 16 + er;
                const float* p = Wih + (size_t)o * 64 + 8 * cp;
                union { ushort u[8]; bf16x8 v; } fr;
                #pragma unroll
                for (int j = 0; j < 8; ++j) fr.u[j] = bf16rn(p[j]);
                wihRZ[g][a] = fr.v;
            }
        #pragma unroll
        for (int g = 0; g < 3; ++g)
            #pragma unroll
            for (int a = 0; a < 4; ++a)
                #pragma unroll
                for (int f = 0; f < 2; ++f) {
                    int o = g * 64 + a * 16 + er;
                    const float* p = Whh + (size_t)o * 64 + 32 * f + 8 * cp;
                    union { ushort u[8]; bf16x8 v; } fr;
                    #pragma unroll
                    for (int j = 0; j < 8; ++j) fr.u[j] = bf16rn(p[j]);
                    whhF[g][a][f] = fr.v;
                }
        // n-gate input-part frags -> LDS (saves 16 VGPR): WnF[a][lane], shared by all waves
        if (wid < 4) {
            int a = wid;
            int o = 128 + a * 16 + er;
            const float* p = Wih + (size_t)o * 64 + 8 * cp;
            union { ushort u[8]; bf16x8 v; } fr;
            #pragma unroll
            for (int j = 0; j < 8; ++j) fr.u[j] = bf16rn(p[j]);
            *(bf16x8*)&WnF[a][lane][0] = fr.v;
        }
    }
    __syncthreads();   // the only barrier

    // ---------- main loop: each wave owns 16 elements, no cross-wave deps ----------
    const long long eg = (long long)(blockIdx.x * 8 + wid) * 16 + er;  // this lane's element
    const float* xr = x + eg * (TN * 2);

    float hold[4][4];   // f32 master copy of h for (elem=er, o = 16a + 4cp + q)
    #pragma unroll
    for (int a = 0; a < 4; ++a)
        #pragma unroll
        for (int q = 0; q < 4; ++q) hold[a][q] = 0.0f;

    float2 xv = *(const float2*)(xr);   // t=0 prefetched

    #pragma unroll 1
    for (int t = 0; t < TN; ++t) {
        // prefetch next step's x (clamped; dead value at t=TN-1)
        const int tn = (t + 1 < TN) ? t + 1 : TN - 1;
        float2 xv_next = *(const float2*)(xr + tn * 2);

        // ex B-frag: ex[k = 8cp+j][elem = er]
        f32x4 w1a = *(const f32x4*)&wlcS[8 * cp];
        f32x4 w1b = *(const f32x4*)&wlcS[8 * cp + 4];
        f32x4 w2a = *(const f32x4*)&wlcS[32 + 8 * cp];
        f32x4 w2b = *(const f32x4*)&wlcS[32 + 8 * cp + 4];
        f32x4 bla = *(const f32x4*)&wlcS[64 + 8 * cp];
        f32x4 blb = *(const f32x4*)&wlcS[64 + 8 * cp + 4];
        union { ushort u[8]; bf16x8 v; } exf;
        #pragma unroll
        for (int j = 0; j < 4; ++j) {
            float v = fmaf(xv.x, w1a[j], fmaf(xv.y, w2a[j], bla[j]));
            v = v > 0.0f ? v : 0.2f * v;
            exf.u[j] = bf16rn(v);
        }
        #pragma unroll
        for (int j = 0; j < 4; ++j) {
            float v = fmaf(xv.x, w1b[j], fmaf(xv.y, w2b[j], blb[j]));
            v = v > 0.0f ? v : 0.2f * v;
            exf.u[4 + j] = bf16rn(v);
        }

        // accumulator init from gic / bhn (f32)
        const float* gt = gicS + t * 192;
        f32x4 accR[4], accZ[4], accNi[4], accNh[4];
        #pragma unroll
        for (int a = 0; a < 4; ++a) {
            accR[a]  = *(const f32x4*)(gt + a * 16 + 4 * cp);
            accZ[a]  = *(const f32x4*)(gt + 64 + a * 16 + 4 * cp);
            accNi[a] = *(const f32x4*)(gt + 128 + a * 16 + 4 * cp);
            accNh[a] = *(const f32x4*)(bhnS + a * 16 + 4 * cp);
        }

        // input-part MFMAs (K=32): D[o×elem] += Wih·exT
        #pragma unroll
        for (int a = 0; a < 4; ++a) {
            accR[a] = __builtin_amdgcn_mfma_f32_16x16x32_bf16(wihRZ[0][a], exf.v, accR[a], 0, 0, 0);
            accZ[a] = __builtin_amdgcn_mfma_f32_16x16x32_bf16(wihRZ[1][a], exf.v, accZ[a], 0, 0, 0);
            bf16x8 wn = *(const bf16x8*)&WnF[a][lane][0];
            accNi[a] = __builtin_amdgcn_mfma_f32_16x16x32_bf16(wn, exf.v, accNi[a], 0, 0, 0);
        }

        // recurrent MFMAs (K=64, h = hi + lo split bf16)
        if (t > 0) {
            bf16x8 hhi0 = *(const bf16x8*)&Hhi[wid][er][8 * cp];
            bf16x8 hhi1 = *(const bf16x8*)&Hhi[wid][er][32 + 8 * cp];
            bf16x8 hlo0 = *(const bf16x8*)&Hlo[wid][er][8 * cp];
            bf16x8 hlo1 = *(const bf16x8*)&Hlo[wid][er][32 + 8 * cp];
            #pragma unroll
            for (int a = 0; a < 4; ++a) {
                accR[a]  = __builtin_amdgcn_mfma_f32_16x16x32_bf16(whhF[0][a][0], hhi0, accR[a], 0, 0, 0);
                accR[a]  = __builtin_amdgcn_mfma_f32_16x16x32_bf16(whhF[0][a][1], hhi1, accR[a], 0, 0, 0);
                accR[a]  = __builtin_amdgcn_mfma_f32_16x16x32_bf16(whhF[0][a][0], hlo0, accR[a], 0, 0, 0);
                accR[a]  = __builtin_amdgcn_mfma_f32_16x16x32_bf16(whhF[0][a][1], hlo1, accR[a], 0, 0, 0);
                accZ[a]  = __builtin_amdgcn_mfma_f32_16x16x32_bf16(whhF[1][a][0], hhi0, accZ[a], 0, 0, 0);
                accZ[a]  = __builtin_amdgcn_mfma_f32_16x16x32_bf16(whhF[1][a][1], hhi1, accZ[a], 0, 0, 0);
                accZ[a]  = __builtin_amdgcn_mfma_f32_16x16x32_bf16(whhF[1][a][0], hlo0, accZ[a], 0, 0, 0);
                accZ[a]  = __builtin_amdgcn_mfma_f32_16x16x32_bf16(whhF[1][a][1], hlo1, accZ[a], 0, 0, 0);
                accNh[a] = __builtin_amdgcn_mfma_f32_16x16x32_bf16(whhF[2][a][0], hhi0, accNh[a], 0, 0, 0);
                accNh[a] = __builtin_amdgcn_mfma_f32_16x16x32_bf16(whhF[2][a][1], hhi1, accNh[a], 0, 0, 0);
                accNh[a] = __builtin_amdgcn_mfma_f32_16x16x32_bf16(whhF[2][a][0], hlo0, accNh[a], 0, 0, 0);
                accNh[a] = __builtin_amdgcn_mfma_f32_16x16x32_bf16(whhF[2][a][1], hlo1, accNh[a], 0, 0, 0);
            }
        }

        // epilogue: gates + h update (f32), pack hi/lo bf16 and store to per-wave LDS
        #pragma unroll
        for (int a = 0; a < 4; ++a) {
            ushort hiu[4], lou[4];
            #pragma unroll
            for (int q = 0; q < 4; ++q) {
                float r  = sigm(accR[a][q]);
                float z  = sigm(accZ[a][q]);
                float np = fmaf(r, accNh[a][q], accNi[a][q]);
                float e2 = __expf(2.0f * np);
                float n  = 1.0f - 2.0f / (e2 + 1.0f);      // tanh
                float h  = n + z * (hold[a][q] - n);
                hold[a][q] = h;
                ushort hi = bf16rn(h);
                hiu[q] = hi;
                lou[q] = bf16rn(h - bf16tof(hi));
            }
            uint2 whi, wlo;
            whi.x = (uint)hiu[0] | ((uint)hiu[1] << 16);
            whi.y = (uint)hiu[2] | ((uint)hiu[3] << 16);
            wlo.x = (uint)lou[0] | ((uint)lou[1] << 16);
            wlo.y = (uint)lou[2] | ((uint)lou[3] << 16);
            *(uint2*)&Hhi[wid][er][16 * a + 4 * cp] = whi;
            *(uint2*)&Hlo[wid][er][16 * a + 4 * cp] = wlo;
        }

        xv = xv_next;
    }

    // ---------- prediction head ----------
    float part = 0.0f;
    #pragma unroll
    for (int a = 0; a < 4; ++a) {
        f32x4 wp = *(const f32x4*)(Wpred + 16 * a + 4 * cp);
        #pragma unroll
        for (int q = 0; q < 4; ++q) part = fmaf(hold[a][q], wp[q], part);
    }
    part += __shfl_xor(part, 16);
    part += __shfl_xor(part, 32);
    if (cp == 0) out[eg] = sigm(part + bpred[0]);
}

extern "C" void kernel_launch(void* const* d_in, const int* in_sizes, int n_in,
                              void* d_out, int out_size, void* d_ws, size_t ws_size,
                              hipStream_t stream) {
    const float* x     = (const float*)d_in[0];
    const float* Wloc  = (const float*)d_in[1];
    const float* bloc  = (const float*)d_in[2];
    const float* tt    = (const float*)d_in[3];
    const float* Wih   = (const float*)d_in[4];
    const float* Whh   = (const float*)d_in[5];
    const float* bih   = (const float*)d_in[6];
    const float* bhh   = (const float*)d_in[7];
    const float* Wpred = (const float*)d_in[8];
    const float* bpred = (const float*)d_in[9];
    float* out = (float*)d_out;

    // 65536 elements / (8 waves * 16 elem) = 512 blocks of 512 threads = 2 blocks/CU
    hipLaunchKernelGGL(traj_gru_mfma, dim3(512), dim3(512), 0, stream,
                       x, Wloc, bloc, tt, Wih, Whh, bih, bhh, Wpred, bpred, out);
}

// Round 4
// 239.300 us; speedup vs baseline: 5.4896x; 5.4896x over previous
//
#include <hip/hip_runtime.h>
#include <hip/hip_bf16.h>

#define TN 24
#define HID 64

// ws layout (bytes):
//   0     : gic [24*192 f32]            (18432)
//   18432 : bhn [64 f32]                (256)
//   18688 : wlc [96 f32]                (384)
//   19072 : frags [36][64] x 16B bf16x8 (36864)   total 55936 B
#define WS_GIC_F   0
#define WS_BHN_F   4608
#define WS_WLC_F   4672
#define WS_FRAG_B  19072

typedef __attribute__((ext_vector_type(8))) short bf16x8;
typedef __attribute__((ext_vector_type(4))) float f32x4;

__device__ __forceinline__ ushort bf16rn(float f) {
    return __builtin_bit_cast(ushort, __float2bfloat16(f));
}
__device__ __forceinline__ float bf16tof(ushort u) {
    return __uint_as_float(((uint)u) << 16);
}
__device__ __forceinline__ float sigm(float v) { return 1.0f / (1.0f + __expf(-v)); }

// ---------------- pre-kernel: build gic + bf16 fragment tables in ws ----------------
extern "C" __global__ void __launch_bounds__(256)
traj_gru_pre(const float* __restrict__ Wloc, const float* __restrict__ bloc,
             const float* __restrict__ tt, const float* __restrict__ Wih,
             const float* __restrict__ Whh, const float* __restrict__ bih,
             const float* __restrict__ bhh, float* __restrict__ ws)
{
    const int b = blockIdx.x, tid = threadIdx.x;
    if (b < 36) {
        // one weight fragment per block; lanes 0..63 produce their 16B slice
        if (tid < 64) {
            const int er = tid & 15, cp = tid >> 4;
            const float* src;
            if (b < 8) {            // wihRZ[g][a], g=b>>2, a=b&3
                int g = b >> 2, a = b & 3;
                src = Wih + (size_t)(g * 64 + a * 16 + er) * 64 + 8 * cp;
            } else if (b < 32) {    // whhF[g][a][f]
                int t = b - 8, g = t >> 3, r = t & 7, a = r >> 1, f = r & 1;
                src = Whh + (size_t)(g * 64 + a * 16 + er) * 64 + 32 * f + 8 * cp;
            } else {                // WnF[a]
                int a = b - 32;
                src = Wih + (size_t)(128 + a * 16 + er) * 64 + 8 * cp;
            }
            union { ushort u[8]; bf16x8 v; } fr;
            #pragma unroll
            for (int j = 0; j < 8; ++j) fr.u[j] = bf16rn(src[j]);
            *(bf16x8*)((char*)ws + WS_FRAG_B + ((size_t)b * 64 + tid) * 16) = fr.v;
        }
    } else if (b < 38) {
        // gic[t][g] = b_ih[g] + (g<128? b_hh[g]:0) + Wih[g][32:]·leaky(tt[t])
        const int base = (b - 36) * 2304;
        for (int i = tid; i < 2304; i += 256) {
            int idx = base + i, t = idx / 192, g = idx % 192;
            float acc = bih[g] + (g < 128 ? bhh[g] : 0.0f);
            const float* ttr = tt + t * 32;
            const float* wr  = Wih + g * 64 + 32;
            #pragma unroll
            for (int k = 0; k < 32; ++k) {
                float e = ttr[k];
                e = e > 0.0f ? e : 0.2f * e;
                acc = fmaf(wr[k], e, acc);
            }
            ws[WS_GIC_F + idx] = acc;
        }
    } else {
        if (tid < 64) ws[WS_BHN_F + tid] = bhh[128 + tid];
        if (tid < 96) ws[WS_WLC_F + tid] = (tid < 64) ? Wloc[tid] : bloc[tid - 64];
    }
}

// ---------------- main kernel ----------------
extern "C" __global__ void __launch_bounds__(256, 2)
traj_gru_mfma(const float* __restrict__ x, const float* __restrict__ ws,
              const float* __restrict__ Wpred, const float* __restrict__ bpred,
              float* __restrict__ out)
{
    __shared__ float gicS[TN * 192];                 // 18432 B
    __shared__ float bhnS[64];
    __shared__ float wlcS[96];
    __shared__ __align__(16) ushort Hhi[4][16][72];  // 9216 B
    __shared__ __align__(16) ushort Hlo[4][16][72];  // 9216 B
    __shared__ __align__(16) ushort WnF[4][64][8];   // 4096 B

    const int tid  = threadIdx.x;
    const int lane = tid & 63;
    const int wid  = tid >> 6;       // wave 0..3
    const int er   = lane & 15;      // A-row / B-col / D-col index
    const int cp   = lane >> 4;      // k-block / D-row-block

    // ---- coalesced setup from ws ----
    {
        const float4* g4 = (const float4*)(ws + WS_GIC_F);
        float4* s4 = (float4*)gicS;
        for (int i = tid; i < (TN * 192) / 4; i += 256) s4[i] = g4[i];
        if (tid < 64) bhnS[tid] = ws[WS_BHN_F + tid];
        if (tid < 96) wlcS[tid] = ws[WS_WLC_F + tid];
    }
    const char* fb = (const char*)ws + WS_FRAG_B;
    bf16x8 wihRZ[2][4];
    bf16x8 whhF[3][4][2];
    #pragma unroll
    for (int g = 0; g < 2; ++g)
        #pragma unroll
        for (int a = 0; a < 4; ++a)
            wihRZ[g][a] = *(const bf16x8*)(fb + ((size_t)(g * 4 + a) * 64 + lane) * 16);
    #pragma unroll
    for (int g = 0; g < 3; ++g)
        #pragma unroll
        for (int a = 0; a < 4; ++a)
            #pragma unroll
            for (int f = 0; f < 2; ++f)
                whhF[g][a][f] = *(const bf16x8*)(fb + ((size_t)(8 + g * 8 + a * 2 + f) * 64 + lane) * 16);
    // WnF staged to LDS: wave wid loads frag 32+wid
    *(bf16x8*)&WnF[wid][lane][0] = *(const bf16x8*)(fb + ((size_t)(32 + wid) * 64 + lane) * 16);
    __syncthreads();   // the only barrier

    // ---- main loop: wave owns 16 elements ----
    const long long eg = (long long)(blockIdx.x * 4 + wid) * 16 + er;
    const float* xr = x + eg * (TN * 2);

    float hold[4][4];
    #pragma unroll
    for (int a = 0; a < 4; ++a)
        #pragma unroll
        for (int q = 0; q < 4; ++q) hold[a][q] = 0.0f;

    float2 xv = *(const float2*)(xr);   // t=0 prefetched

    #pragma unroll 1
    for (int t = 0; t < TN; ++t) {
        const int tn = (t + 1 < TN) ? t + 1 : TN - 1;
        float2 xv_next = *(const float2*)(xr + tn * 2);

        // ex B-frag: ex[k = 8cp+j][elem = er]
        f32x4 w1a = *(const f32x4*)&wlcS[8 * cp];
        f32x4 w1b = *(const f32x4*)&wlcS[8 * cp + 4];
        f32x4 w2a = *(const f32x4*)&wlcS[32 + 8 * cp];
        f32x4 w2b = *(const f32x4*)&wlcS[32 + 8 * cp + 4];
        f32x4 bla = *(const f32x4*)&wlcS[64 + 8 * cp];
        f32x4 blb = *(const f32x4*)&wlcS[64 + 8 * cp + 4];
        union { ushort u[8]; bf16x8 v; } exf;
        #pragma unroll
        for (int j = 0; j < 4; ++j) {
            float v = fmaf(xv.x, w1a[j], fmaf(xv.y, w2a[j], bla[j]));
            v = v > 0.0f ? v : 0.2f * v;
            exf.u[j] = bf16rn(v);
        }
        #pragma unroll
        for (int j = 0; j < 4; ++j) {
            float v = fmaf(xv.x, w1b[j], fmaf(xv.y, w2b[j], blb[j]));
            v = v > 0.0f ? v : 0.2f * v;
            exf.u[4 + j] = bf16rn(v);
        }

        const float* gt = gicS + t * 192;
        f32x4 accR[4], accZ[4], accNi[4], accNh[4];
        #pragma unroll
        for (int a = 0; a < 4; ++a) {
            accR[a]  = *(const f32x4*)(gt + a * 16 + 4 * cp);
            accZ[a]  = *(const f32x4*)(gt + 64 + a * 16 + 4 * cp);
            accNi[a] = *(const f32x4*)(gt + 128 + a * 16 + 4 * cp);
            accNh[a] = *(const f32x4*)(bhnS + a * 16 + 4 * cp);
        }

        #pragma unroll
        for (int a = 0; a < 4; ++a) {
            accR[a] = __builtin_amdgcn_mfma_f32_16x16x32_bf16(wihRZ[0][a], exf.v, accR[a], 0, 0, 0);
            accZ[a] = __builtin_amdgcn_mfma_f32_16x16x32_bf16(wihRZ[1][a], exf.v, accZ[a], 0, 0, 0);
            bf16x8 wn = *(const bf16x8*)&WnF[a][lane][0];
            accNi[a] = __builtin_amdgcn_mfma_f32_16x16x32_bf16(wn, exf.v, accNi[a], 0, 0, 0);
        }

        if (t > 0) {
            bf16x8 hhi0 = *(const bf16x8*)&Hhi[wid][er][8 * cp];
            bf16x8 hhi1 = *(const bf16x8*)&Hhi[wid][er][32 + 8 * cp];
            bf16x8 hlo0 = *(const bf16x8*)&Hlo[wid][er][8 * cp];
            bf16x8 hlo1 = *(const bf16x8*)&Hlo[wid][er][32 + 8 * cp];
            #pragma unroll
            for (int a = 0; a < 4; ++a) {
                accR[a]  = __builtin_amdgcn_mfma_f32_16x16x32_bf16(whhF[0][a][0], hhi0, accR[a], 0, 0, 0);
                accR[a]  = __builtin_amdgcn_mfma_f32_16x16x32_bf16(whhF[0][a][1], hhi1, accR[a], 0, 0, 0);
                accR[a]  = __builtin_amdgcn_mfma_f32_16x16x32_bf16(whhF[0][a][0], hlo0, accR[a], 0, 0, 0);
                accR[a]  = __builtin_amdgcn_mfma_f32_16x16x32_bf16(whhF[0][a][1], hlo1, accR[a], 0, 0, 0);
                accZ[a]  = __builtin_amdgcn_mfma_f32_16x16x32_bf16(whhF[1][a][0], hhi0, accZ[a], 0, 0, 0);
                accZ[a]  = __builtin_amdgcn_mfma_f32_16x16x32_bf16(whhF[1][a][1], hhi1, accZ[a], 0, 0, 0);
                accZ[a]  = __builtin_amdgcn_mfma_f32_16x16x32_bf16(whhF[1][a][0], hlo0, accZ[a], 0, 0, 0);
                accZ[a]  = __builtin_amdgcn_mfma_f32_16x16x32_bf16(whhF[1][a][1], hlo1, accZ[a], 0, 0, 0);
                accNh[a] = __builtin_amdgcn_mfma_f32_16x16x32_bf16(whhF[2][a][0], hhi0, accNh[a], 0, 0, 0);
                accNh[a] = __builtin_amdgcn_mfma_f32_16x16x32_bf16(whhF[2][a][1], hhi1, accNh[a], 0, 0, 0);
                accNh[a] = __builtin_amdgcn_mfma_f32_16x16x32_bf16(whhF[2][a][0], hlo0, accNh[a], 0, 0, 0);
                accNh[a] = __builtin_amdgcn_mfma_f32_16x16x32_bf16(whhF[2][a][1], hlo1, accNh[a], 0, 0, 0);
            }
        }

        #pragma unroll
        for (int a = 0; a < 4; ++a) {
            ushort hiu[4], lou[4];
            #pragma unroll
            for (int q = 0; q < 4; ++q) {
                float r  = sigm(accR[a][q]);
                float z  = sigm(accZ[a][q]);
                float np = fmaf(r, accNh[a][q], accNi[a][q]);
                float e2 = __expf(2.0f * np);
                float n  = 1.0f - 2.0f / (e2 + 1.0f);      // tanh
                float h  = n + z * (hold[a][q] - n);
                hold[a][q] = h;
                ushort hi = bf16rn(h);
                hiu[q] = hi;
                lou[q] = bf16rn(h - bf16tof(hi));
            }
            uint2 whi, wlo;
            whi.x = (uint)hiu[0] | ((uint)hiu[1] << 16);
            whi.y = (uint)hiu[2] | ((uint)hiu[3] << 16);
            wlo.x = (uint)lou[0] | ((uint)lou[1] << 16);
            wlo.y = (uint)lou[2] | ((uint)lou[3] << 16);
            *(uint2*)&Hhi[wid][er][16 * a + 4 * cp] = whi;
            *(uint2*)&Hlo[wid][er][16 * a + 4 * cp] = wlo;
        }

        xv = xv_next;
    }

    // ---- prediction head ----
    float part = 0.0f;
    #pragma unroll
    for (int a = 0; a < 4; ++a) {
        f32x4 wp = *(const f32x4*)(Wpred + 16 * a + 4 * cp);
        #pragma unroll
        for (int q = 0; q < 4; ++q) part = fmaf(hold[a][q], wp[q], part);
    }
    part += __shfl_xor(part, 16);
    part += __shfl_xor(part, 32);
    if (cp == 0) out[eg] = sigm(part + bpred[0]);
}

extern "C" void kernel_launch(void* const* d_in, const int* in_sizes, int n_in,
                              void* d_out, int out_size, void* d_ws, size_t ws_size,
                              hipStream_t stream) {
    const float* x     = (const float*)d_in[0];
    const float* Wloc  = (const float*)d_in[1];
    const float* bloc  = (const float*)d_in[2];
    const float* tt    = (const float*)d_in[3];
    const float* Wih   = (const float*)d_in[4];
    const float* Whh   = (const float*)d_in[5];
    const float* bih   = (const float*)d_in[6];
    const float* bhh   = (const float*)d_in[7];
    const float* Wpred = (const float*)d_in[8];
    const float* bpred = (const float*)d_in[9];
    float* out = (float*)d_out;
    float* ws  = (float*)d_ws;

    hipLaunchKernelGGL(traj_gru_pre, dim3(39), dim3(256), 0, stream,
                       Wloc, bloc, tt, Wih, Whh, bih, bhh, ws);
    // 65536 elements / (4 waves * 16 elem) = 1024 blocks of 256 threads
    hipLaunchKernelGGL(traj_gru_mfma, dim3(1024), dim3(256), 0, stream,
                       x, ws, Wpred, bpred, out);
}

// Round 5
// 180.840 us; speedup vs baseline: 7.2642x; 1.3233x over previous
//
#include <hip/hip_runtime.h>
#include <hip/hip_bf16.h>

#define TN 24
#define HID 64

// ws layout (bytes):
//   0     : gic [24*192 f32]            (18432)
//   18432 : bhn [64 f32]                (256)
//   18688 : wlc [96 f32]                (384)
//   19072 : frags [36][64] x 16B bf16x8 (36864)   total 55936 B
#define WS_GIC_F   0
#define WS_BHN_F   4608
#define WS_WLC_F   4672
#define WS_FRAG_B  19072

typedef __attribute__((ext_vector_type(8))) short bf16x8;
typedef __attribute__((ext_vector_type(4))) float f32x4;

__device__ __forceinline__ ushort bf16rn(float f) {
    uint x = __float_as_uint(f);
    return (ushort)((x + 0x7fffu + ((x >> 16) & 1u)) >> 16);
}
__device__ __forceinline__ float bf16tof(ushort u) {
    return __uint_as_float(((uint)u) << 16);
}
// sigmoid via fast rcp: exact at +-inf (rcp(inf)=0)
__device__ __forceinline__ float sigm(float v) {
    return __builtin_amdgcn_rcpf(1.0f + __expf(-v));
}

// ---------------- pre-kernel: build gic + bf16 fragment tables in ws ----------------
extern "C" __global__ void __launch_bounds__(256)
traj_gru_pre(const float* __restrict__ Wloc, const float* __restrict__ bloc,
             const float* __restrict__ tt, const float* __restrict__ Wih,
             const float* __restrict__ Whh, const float* __restrict__ bih,
             const float* __restrict__ bhh, float* __restrict__ ws)
{
    const int b = blockIdx.x, tid = threadIdx.x;
    if (b < 36) {
        if (tid < 64) {
            const int er = tid & 15, cp = tid >> 4;
            const float* src;
            if (b < 8) {            // wihRZ[g][a], g=b>>2, a=b&3
                int g = b >> 2, a = b & 3;
                src = Wih + (size_t)(g * 64 + a * 16 + er) * 64 + 8 * cp;
            } else if (b < 32) {    // whhF[g][a][f]
                int t = b - 8, g = t >> 3, r = t & 7, a = r >> 1, f = r & 1;
                src = Whh + (size_t)(g * 64 + a * 16 + er) * 64 + 32 * f + 8 * cp;
            } else {                // Wn[a]
                int a = b - 32;
                src = Wih + (size_t)(128 + a * 16 + er) * 64 + 8 * cp;
            }
            union { ushort u[8]; bf16x8 v; } fr;
            #pragma unroll
            for (int j = 0; j < 8; ++j) fr.u[j] = bf16rn(src[j]);
            *(bf16x8*)((char*)ws + WS_FRAG_B + ((size_t)b * 64 + tid) * 16) = fr.v;
        }
    } else if (b < 38) {
        const int base = (b - 36) * 2304;
        for (int i = tid; i < 2304; i += 256) {
            int idx = base + i, t = idx / 192, g = idx % 192;
            float acc = bih[g] + (g < 128 ? bhh[g] : 0.0f);
            const float* ttr = tt + t * 32;
            const float* wr  = Wih + g * 64 + 32;
            #pragma unroll
            for (int k = 0; k < 32; ++k) {
                float e = ttr[k];
                e = e > 0.0f ? e : 0.2f * e;
                acc = fmaf(wr[k], e, acc);
            }
            ws[WS_GIC_F + idx] = acc;
        }
    } else {
        if (tid < 64) ws[WS_BHN_F + tid] = bhh[128 + tid];
        if (tid < 96) ws[WS_WLC_F + tid] = (tid < 64) ? Wloc[tid] : bloc[tid - 64];
    }
}

// ---------------- main kernel ----------------
extern "C" __global__ void __launch_bounds__(256, 2)
traj_gru_mfma(const float* __restrict__ x, const float* __restrict__ ws,
              const float* __restrict__ Wpred, const float* __restrict__ bpred,
              float* __restrict__ out)
{
    // LDS: 18432 + 256 + 384 + 9216 + 9216 + 12288 = 49792 B
    __shared__ float gicS[TN * 192];
    __shared__ float bhnS[64];
    __shared__ float wlcS[96];
    __shared__ __align__(16) ushort Hhi[4][16][72];
    __shared__ __align__(16) ushort Hlo[4][16][72];
    __shared__ __align__(16) ushort WiS[12][64][8];  // 0-3 wihR[a], 4-7 wihZ[a], 8-11 wn[a]

    const int tid  = threadIdx.x;
    const int lane = tid & 63;
    const int wid  = tid >> 6;       // wave 0..3
    const int er   = lane & 15;      // A-row / B-col / D-col index
    const int cp   = lane >> 4;      // k-block / D-row-block

    // ---- coalesced setup from ws ----
    {
        const float4* g4 = (const float4*)(ws + WS_GIC_F);
        float4* s4 = (float4*)gicS;
        for (int i = tid; i < (TN * 192) / 4; i += 256) s4[i] = g4[i];
        if (tid < 64) bhnS[tid] = ws[WS_BHN_F + tid];
        if (tid < 96) wlcS[tid] = ws[WS_WLC_F + tid];
    }
    const char* fb = (const char*)ws + WS_FRAG_B;
    // input-side frags -> LDS (12 frags x 64 lanes x 16B)
    #pragma unroll
    for (int i = 0; i < 3; ++i) {
        int chunk = i * 256 + tid;          // 0..767
        int fr = chunk >> 6, ln = chunk & 63;
        int srcf = fr < 8 ? fr : fr + 24;   // wn frags live at ws index 32..35
        *(bf16x8*)&WiS[fr][ln][0] = *(const bf16x8*)(fb + ((size_t)srcf * 64 + ln) * 16);
    }
    // recurrent frags -> registers (24 x 4 VGPR)
    bf16x8 whhF[3][4][2];
    #pragma unroll
    for (int g = 0; g < 3; ++g)
        #pragma unroll
        for (int a = 0; a < 4; ++a)
            #pragma unroll
            for (int f = 0; f < 2; ++f)
                whhF[g][a][f] = *(const bf16x8*)(fb + ((size_t)(8 + g * 8 + a * 2 + f) * 64 + lane) * 16);
    __syncthreads();   // the only barrier

    // ---- main loop: wave owns 16 elements ----
    const long long eg = (long long)(blockIdx.x * 4 + wid) * 16 + er;
    const float* xr = x + eg * (TN * 2);

    float hold[4][4];
    #pragma unroll
    for (int a = 0; a < 4; ++a)
        #pragma unroll
        for (int q = 0; q < 4; ++q) hold[a][q] = 0.0f;

    float2 xv = *(const float2*)(xr);   // t=0 prefetched

    #pragma unroll 1
    for (int t = 0; t < TN; ++t) {
        const int tn = (t + 1 < TN) ? t + 1 : TN - 1;
        float2 xv_next = *(const float2*)(xr + tn * 2);

        // ex B-frag: ex[k = 8cp+j][elem = er]
        f32x4 w1a = *(const f32x4*)&wlcS[8 * cp];
        f32x4 w1b = *(const f32x4*)&wlcS[8 * cp + 4];
        f32x4 w2a = *(const f32x4*)&wlcS[32 + 8 * cp];
        f32x4 w2b = *(const f32x4*)&wlcS[32 + 8 * cp + 4];
        f32x4 bla = *(const f32x4*)&wlcS[64 + 8 * cp];
        f32x4 blb = *(const f32x4*)&wlcS[64 + 8 * cp + 4];
        union { ushort u[8]; bf16x8 v; } exf;
        #pragma unroll
        for (int j = 0; j < 4; ++j) {
            float v = fmaf(xv.x, w1a[j], fmaf(xv.y, w2a[j], bla[j]));
            v = v > 0.0f ? v : 0.2f * v;
            exf.u[j] = bf16rn(v);
        }
        #pragma unroll
        for (int j = 0; j < 4; ++j) {
            float v = fmaf(xv.x, w1b[j], fmaf(xv.y, w2b[j], blb[j]));
            v = v > 0.0f ? v : 0.2f * v;
            exf.u[4 + j] = bf16rn(v);
        }

        const float* gt = gicS + t * 192;
        f32x4 accR[4], accZ[4], accNi[4], accNh[4];
        #pragma unroll
        for (int a = 0; a < 4; ++a) {
            accR[a]  = *(const f32x4*)(gt + a * 16 + 4 * cp);
            accZ[a]  = *(const f32x4*)(gt + 64 + a * 16 + 4 * cp);
            accNi[a] = *(const f32x4*)(gt + 128 + a * 16 + 4 * cp);
            accNh[a] = *(const f32x4*)(bhnS + a * 16 + 4 * cp);
        }

        // input-part MFMAs (K=32), weights streamed from LDS
        #pragma unroll
        for (int a = 0; a < 4; ++a) {
            bf16x8 wr = *(const bf16x8*)&WiS[a][lane][0];
            bf16x8 wz = *(const bf16x8*)&WiS[4 + a][lane][0];
            bf16x8 wn = *(const bf16x8*)&WiS[8 + a][lane][0];
            accR[a]  = __builtin_amdgcn_mfma_f32_16x16x32_bf16(wr, exf.v, accR[a], 0, 0, 0);
            accZ[a]  = __builtin_amdgcn_mfma_f32_16x16x32_bf16(wz, exf.v, accZ[a], 0, 0, 0);
            accNi[a] = __builtin_amdgcn_mfma_f32_16x16x32_bf16(wn, exf.v, accNi[a], 0, 0, 0);
        }

        // recurrent MFMAs (K=64, h = hi + lo split bf16)
        if (t > 0) {
            bf16x8 hhi0 = *(const bf16x8*)&Hhi[wid][er][8 * cp];
            bf16x8 hhi1 = *(const bf16x8*)&Hhi[wid][er][32 + 8 * cp];
            bf16x8 hlo0 = *(const bf16x8*)&Hlo[wid][er][8 * cp];
            bf16x8 hlo1 = *(const bf16x8*)&Hlo[wid][er][32 + 8 * cp];
            #pragma unroll
            for (int a = 0; a < 4; ++a) {
                accR[a]  = __builtin_amdgcn_mfma_f32_16x16x32_bf16(whhF[0][a][0], hhi0, accR[a], 0, 0, 0);
                accR[a]  = __builtin_amdgcn_mfma_f32_16x16x32_bf16(whhF[0][a][1], hhi1, accR[a], 0, 0, 0);
                accR[a]  = __builtin_amdgcn_mfma_f32_16x16x32_bf16(whhF[0][a][0], hlo0, accR[a], 0, 0, 0);
                accR[a]  = __builtin_amdgcn_mfma_f32_16x16x32_bf16(whhF[0][a][1], hlo1, accR[a], 0, 0, 0);
                accZ[a]  = __builtin_amdgcn_mfma_f32_16x16x32_bf16(whhF[1][a][0], hhi0, accZ[a], 0, 0, 0);
                accZ[a]  = __builtin_amdgcn_mfma_f32_16x16x32_bf16(whhF[1][a][1], hhi1, accZ[a], 0, 0, 0);
                accZ[a]  = __builtin_amdgcn_mfma_f32_16x16x32_bf16(whhF[1][a][0], hlo0, accZ[a], 0, 0, 0);
                accZ[a]  = __builtin_amdgcn_mfma_f32_16x16x32_bf16(whhF[1][a][1], hlo1, accZ[a], 0, 0, 0);
                accNh[a] = __builtin_amdgcn_mfma_f32_16x16x32_bf16(whhF[2][a][0], hhi0, accNh[a], 0, 0, 0);
                accNh[a] = __builtin_amdgcn_mfma_f32_16x16x32_bf16(whhF[2][a][1], hhi1, accNh[a], 0, 0, 0);
                accNh[a] = __builtin_amdgcn_mfma_f32_16x16x32_bf16(whhF[2][a][0], hlo0, accNh[a], 0, 0, 0);
                accNh[a] = __builtin_amdgcn_mfma_f32_16x16x32_bf16(whhF[2][a][1], hlo1, accNh[a], 0, 0, 0);
            }
        }

        // epilogue: gates + h update (f32, rcp-based), pack hi/lo bf16 -> LDS
        #pragma unroll
        for (int a = 0; a < 4; ++a) {
            ushort hiu[4], lou[4];
            #pragma unroll
            for (int q = 0; q < 4; ++q) {
                float r  = sigm(accR[a][q]);
                float z  = sigm(accZ[a][q]);
                float np = fmaf(r, accNh[a][q], accNi[a][q]);
                float e2 = __expf(2.0f * np);
                float n  = 1.0f - 2.0f * __builtin_amdgcn_rcpf(e2 + 1.0f);  // tanh, inf-safe
                float h  = n + z * (hold[a][q] - n);
                hold[a][q] = h;
                ushort hi = bf16rn(h);
                hiu[q] = hi;
                lou[q] = bf16rn(h - bf16tof(hi));
            }
            uint2 whi, wlo;
            whi.x = (uint)hiu[0] | ((uint)hiu[1] << 16);
            whi.y = (uint)hiu[2] | ((uint)hiu[3] << 16);
            wlo.x = (uint)lou[0] | ((uint)lou[1] << 16);
            wlo.y = (uint)lou[2] | ((uint)lou[3] << 16);
            *(uint2*)&Hhi[wid][er][16 * a + 4 * cp] = whi;
            *(uint2*)&Hlo[wid][er][16 * a + 4 * cp] = wlo;
        }

        xv = xv_next;
    }

    // ---- prediction head ----
    float part = 0.0f;
    #pragma unroll
    for (int a = 0; a < 4; ++a) {
        f32x4 wp = *(const f32x4*)(Wpred + 16 * a + 4 * cp);
        #pragma unroll
        for (int q = 0; q < 4; ++q) part = fmaf(hold[a][q], wp[q], part);
    }
    part += __shfl_xor(part, 16);
    part += __shfl_xor(part, 32);
    if (cp == 0) out[eg] = sigm(part + bpred[0]);
}

extern "C" void kernel_launch(void* const* d_in, const int* in_sizes, int n_in,
                              void* d_out, int out_size, void* d_ws, size_t ws_size,
                              hipStream_t stream) {
    const float* x     = (const float*)d_in[0];
    const float* Wloc  = (const float*)d_in[1];
    const float* bloc  = (const float*)d_in[2];
    const float* tt    = (const float*)d_in[3];
    const float* Wih   = (const float*)d_in[4];
    const float* Whh   = (const float*)d_in[5];
    const float* bih   = (const float*)d_in[6];
    const float* bhh   = (const float*)d_in[7];
    const float* Wpred = (const float*)d_in[8];
    const float* bpred = (const float*)d_in[9];
    float* out = (float*)d_out;
    float* ws  = (float*)d_ws;

    hipLaunchKernelGGL(traj_gru_pre, dim3(39), dim3(256), 0, stream,
                       Wloc, bloc, tt, Wih, Whh, bih, bhh, ws);
    hipLaunchKernelGGL(traj_gru_mfma, dim3(1024), dim3(256), 0, stream,
                       x, ws, Wpred, bpred, out);
}

// Round 6
// 135.491 us; speedup vs baseline: 9.6956x; 1.3347x over previous
//
#include <hip/hip_runtime.h>
#include <hip/hip_bf16.h>

#define TN 24
#define HID 64

// ws layout (bytes):
//   0     : gic [24*192 f32]            (18432)
//   18432 : bhn [64 f32]                (256)
//   18688 : wlc [96 f32]                (384)
//   19072 : frags [36][64] x 16B bf16x8 (36864)   total 55936 B
#define WS_GIC_F   0
#define WS_BHN_F   4608
#define WS_WLC_F   4672
#define WS_FRAG_B  19072

// dynamic LDS layout (bytes), total 74368:
#define HHI_OFF  0        // ushort [8][16][72]  18432
#define HLO_OFF  18432    // ushort [8][16][72]  18432
#define WHH_OFF  36864    // 24 frags x 64 lanes x 16B  24576
#define WI_OFF   61440    // 12 frags x 64 lanes x 16B  12288
#define BHN_OFF  73728    // 64 f32
#define WLC_OFF  73984    // 96 f32
#define LDS_BYTES 74368

typedef __attribute__((ext_vector_type(8))) short bf16x8;
typedef __attribute__((ext_vector_type(4))) float f32x4;

__device__ __forceinline__ ushort bf16rn(float f) {
    uint x = __float_as_uint(f);
    return (ushort)((x + 0x7fffu + ((x >> 16) & 1u)) >> 16);
}
__device__ __forceinline__ uint cvtpk_bf16(float lo, float hi) {
    uint r;
    asm("v_cvt_pk_bf16_f32 %0, %1, %2" : "=v"(r) : "v"(lo), "v"(hi));
    return r;
}
// sigmoid via fast rcp: exact at +-inf (rcp(inf)=0)
__device__ __forceinline__ float sigm(float v) {
    return __builtin_amdgcn_rcpf(1.0f + __expf(-v));
}

// ---------------- pre-kernel: build gic + bf16 fragment tables in ws ----------------
extern "C" __global__ void __launch_bounds__(256)
traj_gru_pre(const float* __restrict__ Wloc, const float* __restrict__ bloc,
             const float* __restrict__ tt, const float* __restrict__ Wih,
             const float* __restrict__ Whh, const float* __restrict__ bih,
             const float* __restrict__ bhh, float* __restrict__ ws)
{
    const int b = blockIdx.x, tid = threadIdx.x;
    if (b < 36) {
        if (tid < 64) {
            const int er = tid & 15, cp = tid >> 4;
            const float* src;
            if (b < 8) {            // wihRZ[g][a], g=b>>2, a=b&3
                int g = b >> 2, a = b & 3;
                src = Wih + (size_t)(g * 64 + a * 16 + er) * 64 + 8 * cp;
            } else if (b < 32) {    // whhF[g][a][f]
                int t = b - 8, g = t >> 3, r = t & 7, a = r >> 1, f = r & 1;
                src = Whh + (size_t)(g * 64 + a * 16 + er) * 64 + 32 * f + 8 * cp;
            } else {                // Wn[a]
                int a = b - 32;
                src = Wih + (size_t)(128 + a * 16 + er) * 64 + 8 * cp;
            }
            union { ushort u[8]; bf16x8 v; } fr;
            #pragma unroll
            for (int j = 0; j < 8; ++j) fr.u[j] = bf16rn(src[j]);
            *(bf16x8*)((char*)ws + WS_FRAG_B + ((size_t)b * 64 + tid) * 16) = fr.v;
        }
    } else if (b < 38) {
        const int base = (b - 36) * 2304;
        for (int i = tid; i < 2304; i += 256) {
            int idx = base + i, t = idx / 192, g = idx % 192;
            float acc = bih[g] + (g < 128 ? bhh[g] : 0.0f);
            const float* ttr = tt + t * 32;
            const float* wr  = Wih + g * 64 + 32;
            #pragma unroll
            for (int k = 0; k < 32; ++k) {
                float e = ttr[k];
                e = fmaxf(e, 0.2f * e);
                acc = fmaf(wr[k], e, acc);
            }
            ws[WS_GIC_F + idx] = acc;
        }
    } else {
        if (tid < 64) ws[WS_BHN_F + tid] = bhh[128 + tid];
        if (tid < 96) ws[WS_WLC_F + tid] = (tid < 64) ? Wloc[tid] : bloc[tid - 64];
    }
}

// ---------------- main kernel ----------------
extern "C" __global__ void __launch_bounds__(512, 4)
traj_gru_mfma(const float* __restrict__ x, const float* __restrict__ ws,
              const float* __restrict__ Wpred, const float* __restrict__ bpred,
              float* __restrict__ out)
{
    extern __shared__ __align__(16) char L[];
    float*  Lf   = (float*)L;
    char*   whhS = L + WHH_OFF;
    char*   wiS  = L + WI_OFF;

    const int tid  = threadIdx.x;
    const int lane = tid & 63;
    const int wid  = tid >> 6;       // wave 0..7
    const int er   = lane & 15;      // A-row / B-col / D-col index
    const int cp   = lane >> 4;      // k-block / D-row-block

    // ---- stage all 36 weight frags ws -> LDS (coalesced 16B chunks) ----
    const char* fb = (const char*)ws + WS_FRAG_B;
    for (int i = tid; i < 36 * 64; i += 512) {
        int f = i >> 6, l = i & 63;
        bf16x8 v = *(const bf16x8*)(fb + (size_t)i * 16);
        char* dst;
        if (f < 8)       dst = wiS  + ((size_t)f * 64 + l) * 16;        // R,Z input frags
        else if (f < 32) dst = whhS + ((size_t)(f - 8) * 64 + l) * 16;  // recurrent frags
        else             dst = wiS  + ((size_t)(f - 24) * 64 + l) * 16; // n input frags -> 8..11
        *(bf16x8*)dst = v;
    }
    if (tid < 64) Lf[BHN_OFF / 4 + tid] = ws[WS_BHN_F + tid];
    if (tid < 96) Lf[WLC_OFF / 4 + tid] = ws[WS_WLC_F + tid];
    __syncthreads();   // the only barrier

    const float* wlcS = Lf + WLC_OFF / 4;
    ushort* Hhi = (ushort*)(L + HHI_OFF) + (size_t)(wid * 16) * 72;
    ushort* Hlo = (ushort*)(L + HLO_OFF) + (size_t)(wid * 16) * 72;

    // ---- main loop: wave owns 16 elements ----
    const long long eg = (long long)(blockIdx.x * 8 + wid) * 16 + er;
    const float* xr = x + eg * (TN * 2);

    float hold[4][4];
    #pragma unroll
    for (int a = 0; a < 4; ++a)
        #pragma unroll
        for (int q = 0; q < 4; ++q) hold[a][q] = 0.0f;

    float2 xv = *(const float2*)(xr);   // t=0 prefetched

    #pragma unroll 1
    for (int t = 0; t < TN; ++t) {
        const int tn = (t + 1 < TN) ? t + 1 : TN - 1;
        float2 xv_next = *(const float2*)(xr + tn * 2);

        // ex B-frag: ex[k = 8cp+j][elem = er]
        union { uint u[4]; bf16x8 v; } exf;
        {
            float e[8];
            #pragma unroll
            for (int j = 0; j < 8; ++j) {
                int k = 8 * cp + j;  // cp wave-uniform within lane group; LDS broadcast
                float v = fmaf(xv.x, wlcS[k], fmaf(xv.y, wlcS[32 + k], wlcS[64 + k]));
                e[j] = fmaxf(v, 0.2f * v);
            }
            exf.u[0] = cvtpk_bf16(e[0], e[1]);
            exf.u[1] = cvtpk_bf16(e[2], e[3]);
            exf.u[2] = cvtpk_bf16(e[4], e[5]);
            exf.u[3] = cvtpk_bf16(e[6], e[7]);
        }

        // accumulator init: gic from global (L1-resident), bhn from LDS
        const float* gt = ws + WS_GIC_F + t * 192;
        f32x4 accR[4], accZ[4], accNi[4], accNh[4];
        #pragma unroll
        for (int a = 0; a < 4; ++a) {
            accR[a]  = *(const f32x4*)(gt + a * 16 + 4 * cp);
            accZ[a]  = *(const f32x4*)(gt + 64 + a * 16 + 4 * cp);
            accNi[a] = *(const f32x4*)(gt + 128 + a * 16 + 4 * cp);
            accNh[a] = *(const f32x4*)(Lf + BHN_OFF / 4 + a * 16 + 4 * cp);
        }

        // input-part MFMAs (K=32), weights from LDS
        #pragma unroll
        for (int a = 0; a < 4; ++a) {
            bf16x8 wr = *(const bf16x8*)(wiS + ((size_t)a * 64 + lane) * 16);
            bf16x8 wz = *(const bf16x8*)(wiS + ((size_t)(4 + a) * 64 + lane) * 16);
            bf16x8 wn = *(const bf16x8*)(wiS + ((size_t)(8 + a) * 64 + lane) * 16);
            accR[a]  = __builtin_amdgcn_mfma_f32_16x16x32_bf16(wr, exf.v, accR[a], 0, 0, 0);
            accZ[a]  = __builtin_amdgcn_mfma_f32_16x16x32_bf16(wz, exf.v, accZ[a], 0, 0, 0);
            accNi[a] = __builtin_amdgcn_mfma_f32_16x16x32_bf16(wn, exf.v, accNi[a], 0, 0, 0);
        }

        // recurrent MFMAs (K=64, h = hi + lo split bf16), weights from LDS
        if (t > 0) {
            bf16x8 hhi0 = *(const bf16x8*)&Hhi[er * 72 + 8 * cp];
            bf16x8 hhi1 = *(const bf16x8*)&Hhi[er * 72 + 32 + 8 * cp];
            bf16x8 hlo0 = *(const bf16x8*)&Hlo[er * 72 + 8 * cp];
            bf16x8 hlo1 = *(const bf16x8*)&Hlo[er * 72 + 32 + 8 * cp];
            #pragma unroll
            for (int g = 0; g < 3; ++g) {
                #pragma unroll
                for (int a = 0; a < 4; ++a) {
                    bf16x8 w0 = *(const bf16x8*)(whhS + ((size_t)(g * 8 + a * 2 + 0) * 64 + lane) * 16);
                    bf16x8 w1 = *(const bf16x8*)(whhS + ((size_t)(g * 8 + a * 2 + 1) * 64 + lane) * 16);
                    f32x4* acc = (g == 0) ? &accR[a] : (g == 1) ? &accZ[a] : &accNh[a];
                    f32x4 c = *acc;
                    c = __builtin_amdgcn_mfma_f32_16x16x32_bf16(w0, hhi0, c, 0, 0, 0);
                    c = __builtin_amdgcn_mfma_f32_16x16x32_bf16(w1, hhi1, c, 0, 0, 0);
                    c = __builtin_amdgcn_mfma_f32_16x16x32_bf16(w0, hlo0, c, 0, 0, 0);
                    c = __builtin_amdgcn_mfma_f32_16x16x32_bf16(w1, hlo1, c, 0, 0, 0);
                    *acc = c;
                }
            }
        }

        // epilogue: gates + h update (f32), cvt_pk packing -> LDS
        #pragma unroll
        for (int a = 0; a < 4; ++a) {
            float h[4];
            #pragma unroll
            for (int q = 0; q < 4; ++q) {
                float r  = sigm(accR[a][q]);
                float z  = sigm(accZ[a][q]);
                float np = fmaf(r, accNh[a][q], accNi[a][q]);
                float e2 = __expf(2.0f * np);
                float n  = fmaf(-2.0f, __builtin_amdgcn_rcpf(e2 + 1.0f), 1.0f);  // tanh
                h[q] = fmaf(z, hold[a][q] - n, n);
                hold[a][q] = h[q];
            }
            uint2 whi;
            whi.x = cvtpk_bf16(h[0], h[1]);
            whi.y = cvtpk_bf16(h[2], h[3]);
            float l0 = h[0] - __uint_as_float(whi.x << 16);
            float l1 = h[1] - __uint_as_float(whi.x & 0xffff0000u);
            float l2 = h[2] - __uint_as_float(whi.y << 16);
            float l3 = h[3] - __uint_as_float(whi.y & 0xffff0000u);
            uint2 wlo;
            wlo.x = cvtpk_bf16(l0, l1);
            wlo.y = cvtpk_bf16(l2, l3);
            *(uint2*)&Hhi[er * 72 + 16 * a + 4 * cp] = whi;
            *(uint2*)&Hlo[er * 72 + 16 * a + 4 * cp] = wlo;
        }

        xv = xv_next;
    }

    // ---- prediction head ----
    float part = 0.0f;
    #pragma unroll
    for (int a = 0; a < 4; ++a) {
        f32x4 wp = *(const f32x4*)(Wpred + 16 * a + 4 * cp);
        #pragma unroll
        for (int q = 0; q < 4; ++q) part = fmaf(hold[a][q], wp[q], part);
    }
    part += __shfl_xor(part, 16);
    part += __shfl_xor(part, 32);
    if (cp == 0) out[eg] = sigm(part + bpred[0]);
}

extern "C" void kernel_launch(void* const* d_in, const int* in_sizes, int n_in,
                              void* d_out, int out_size, void* d_ws, size_t ws_size,
                              hipStream_t stream) {
    const float* x     = (const float*)d_in[0];
    const float* Wloc  = (const float*)d_in[1];
    const float* bloc  = (const float*)d_in[2];
    const float* tt    = (const float*)d_in[3];
    const float* Wih   = (const float*)d_in[4];
    const float* Whh   = (const float*)d_in[5];
    const float* bih   = (const float*)d_in[6];
    const float* bhh   = (const float*)d_in[7];
    const float* Wpred = (const float*)d_in[8];
    const float* bpred = (const float*)d_in[9];
    float* out = (float*)d_out;
    float* ws  = (float*)d_ws;

    // deterministic, idempotent host-side attribute set (>64KB dynamic LDS)
    (void)hipFuncSetAttribute((const void*)traj_gru_mfma,
                              hipFuncAttributeMaxDynamicSharedMemorySize, LDS_BYTES);

    hipLaunchKernelGGL(traj_gru_pre, dim3(39), dim3(256), 0, stream,
                       Wloc, bloc, tt, Wih, Whh, bih, bhh, ws);
    // 65536 elements / (8 waves * 16 elem) = 512 blocks, 2/CU, all resident
    hipLaunchKernelGGL(traj_gru_mfma, dim3(512), dim3(512), LDS_BYTES, stream,
                       x, ws, Wpred, bpred, out);
}

// Round 7
// 119.210 us; speedup vs baseline: 11.0198x; 1.1366x over previous
//
#include <hip/hip_runtime.h>
#include <hip/hip_bf16.h>

#define TN 24
#define HID 64
#define LOG2E 1.4426950408889634f

// ws layout (bytes):
//   0     : gic [24*192 f32]  (scaled by log2e / 2log2e)   (18432)
//   18432 : bhn [64 f32]      (scaled by 2log2e)           (256)
//   18688 : wlc [96 f32]      (unscaled)                   (384)
//   19072 : frags [36][64] x 16B bf16x8 (scaled)           (36864)
#define WS_GIC_F   0
#define WS_BHN_F   4608
#define WS_WLC_F   4672
#define WS_FRAG_B  19072

// dynamic LDS layout (bytes), total 74368:
#define HHI_OFF  0        // ushort [8][16][72]  18432
#define HLO_OFF  18432    // ushort [8][16][72]  18432
#define WHH_OFF  36864    // 24 frags x 64 lanes x 16B  24576
#define WI_OFF   61440    // 12 frags x 64 lanes x 16B  12288
#define BHN_OFF  73728    // 64 f32
#define WLC_OFF  73984    // 96 f32
#define LDS_BYTES 74368

typedef __attribute__((ext_vector_type(8))) short bf16x8;
typedef __attribute__((ext_vector_type(4))) float f32x4;
typedef __attribute__((ext_vector_type(2))) float f32x2;

__device__ __forceinline__ ushort bf16rn(float f) {
    uint x = __float_as_uint(f);
    return (ushort)((x + 0x7fffu + ((x >> 16) & 1u)) >> 16);
}
__device__ __forceinline__ uint cvtpk_bf16(float lo, float hi) {
    uint r;
    asm("v_cvt_pk_bf16_f32 %0, %1, %2" : "=v"(r) : "v"(lo), "v"(hi));
    return r;
}
__device__ __forceinline__ float exp2p_(float x) {   // 2^x
    float r; asm("v_exp_f32 %0, %1" : "=v"(r) : "v"(x)); return r;
}
__device__ __forceinline__ float exp2n_(float x) {   // 2^-x (free neg modifier)
    float r; asm("v_exp_f32 %0, -%1" : "=v"(r) : "v"(x)); return r;
}
__device__ __forceinline__ float sigm(float v) {
    return __builtin_amdgcn_rcpf(1.0f + __expf(-v));
}

// ---------------- pre-kernel: build scaled gic + bf16 fragment tables in ws ----------------
extern "C" __global__ void __launch_bounds__(256)
traj_gru_pre(const float* __restrict__ Wloc, const float* __restrict__ bloc,
             const float* __restrict__ tt, const float* __restrict__ Wih,
             const float* __restrict__ Whh, const float* __restrict__ bih,
             const float* __restrict__ bhh, float* __restrict__ ws)
{
    const int b = blockIdx.x, tid = threadIdx.x;
    if (b < 36) {
        if (tid < 64) {
            const int er = tid & 15, cp = tid >> 4;
            const float* src;
            float s;
            if (b < 8) {            // wih R (0-3), Z (4-7): scale log2e
                int g = b >> 2, a = b & 3;
                src = Wih + (size_t)(g * 64 + a * 16 + er) * 64 + 8 * cp;
                s = LOG2E;
            } else if (b < 32) {    // whh frags: r,z -> log2e; n -> 2log2e
                int t = b - 8, g = t >> 3, r = t & 7, a = r >> 1, f = r & 1;
                src = Whh + (size_t)(g * 64 + a * 16 + er) * 64 + 32 * f + 8 * cp;
                s = (g == 2) ? 2.0f * LOG2E : LOG2E;
            } else {                // wih n-gate: 2log2e
                int a = b - 32;
                src = Wih + (size_t)(128 + a * 16 + er) * 64 + 8 * cp;
                s = 2.0f * LOG2E;
            }
            union { ushort u[8]; bf16x8 v; } fr;
            #pragma unroll
            for (int j = 0; j < 8; ++j) fr.u[j] = bf16rn(s * src[j]);
            *(bf16x8*)((char*)ws + WS_FRAG_B + ((size_t)b * 64 + tid) * 16) = fr.v;
        }
    } else if (b < 38) {
        const int base = (b - 36) * 2304;
        for (int i = tid; i < 2304; i += 256) {
            int idx = base + i, t = idx / 192, g = idx % 192;
            float acc = bih[g] + (g < 128 ? bhh[g] : 0.0f);
            const float* ttr = tt + t * 32;
            const float* wr  = Wih + g * 64 + 32;
            #pragma unroll
            for (int k = 0; k < 32; ++k) {
                float e = ttr[k];
                e = fmaxf(e, 0.2f * e);
                acc = fmaf(wr[k], e, acc);
            }
            ws[WS_GIC_F + idx] = acc * (g < 128 ? LOG2E : 2.0f * LOG2E);
        }
    } else {
        if (tid < 64) ws[WS_BHN_F + tid] = 2.0f * LOG2E * bhh[128 + tid];
        if (tid < 96) ws[WS_WLC_F + tid] = (tid < 64) ? Wloc[tid] : bloc[tid - 64];
    }
}

// ---------------- main kernel ----------------
extern "C" __global__ void __launch_bounds__(512, 4)
traj_gru_mfma(const float* __restrict__ x, const float* __restrict__ ws,
              const float* __restrict__ Wpred, const float* __restrict__ bpred,
              float* __restrict__ out)
{
    extern __shared__ __align__(16) char L[];
    float*  Lf   = (float*)L;
    char*   whhS = L + WHH_OFF;
    char*   wiS  = L + WI_OFF;

    const int tid  = threadIdx.x;
    const int lane = tid & 63;
    const int wid  = tid >> 6;       // wave 0..7
    const int er   = lane & 15;      // A-row / B-col / D-col index
    const int cp   = lane >> 4;      // k-block / D-row-block

    // ---- stage all 36 weight frags ws -> LDS (coalesced 16B chunks) ----
    const char* fb = (const char*)ws + WS_FRAG_B;
    for (int i = tid; i < 36 * 64; i += 512) {
        int f = i >> 6, l = i & 63;
        bf16x8 v = *(const bf16x8*)(fb + (size_t)i * 16);
        char* dst;
        if (f < 8)       dst = wiS  + ((size_t)f * 64 + l) * 16;        // R,Z input frags
        else if (f < 32) dst = whhS + ((size_t)(f - 8) * 64 + l) * 16;  // recurrent frags
        else             dst = wiS  + ((size_t)(f - 24) * 64 + l) * 16; // n input frags -> 8..11
        *(bf16x8*)dst = v;
    }
    if (tid < 64) Lf[BHN_OFF / 4 + tid] = ws[WS_BHN_F + tid];
    if (tid < 96) Lf[WLC_OFF / 4 + tid] = ws[WS_WLC_F + tid];
    __syncthreads();   // the only barrier

    const f32x2* wlc2 = (const f32x2*)(Lf + WLC_OFF / 4);
    ushort* Hhi = (ushort*)(L + HHI_OFF) + (size_t)(wid * 16) * 72;
    ushort* Hlo = (ushort*)(L + HLO_OFF) + (size_t)(wid * 16) * 72;

    // ---- main loop: wave owns 16 elements ----
    const long long eg = (long long)(blockIdx.x * 8 + wid) * 16 + er;
    const float* xr = x + eg * (TN * 2);

    f32x2 hold2[4][2];
    #pragma unroll
    for (int a = 0; a < 4; ++a)
        #pragma unroll
        for (int p = 0; p < 2; ++p) hold2[a][p] = (f32x2){0.0f, 0.0f};

    const f32x2 one2    = {1.0f, 1.0f};
    const f32x2 negtwo2 = {-2.0f, -2.0f};

    float2 xv = *(const float2*)(xr);   // t=0 prefetched

    #pragma unroll 1
    for (int t = 0; t < TN; ++t) {
        const int tn = (t + 1 < TN) ? t + 1 : TN - 1;
        float2 xv_next = *(const float2*)(xr + tn * 2);

        // ex B-frag: ex[k = 8cp+j][elem = er], built in f32x2 pairs (pk fma)
        union { uint u[4]; bf16x8 v; } exf;
        {
            f32x2 xx = {xv.x, xv.x}, yy = {xv.y, xv.y};
            #pragma unroll
            for (int jp = 0; jp < 4; ++jp) {
                int kp = 4 * cp + jp;   // k pair index
                f32x2 w1 = wlc2[kp], w2 = wlc2[16 + kp], bl = wlc2[32 + kp];
                f32x2 v = __builtin_elementwise_fma(xx, w1,
                          __builtin_elementwise_fma(yy, w2, bl));
                float v0 = fmaxf(v.x, 0.2f * v.x);
                float v1 = fmaxf(v.y, 0.2f * v.y);
                exf.u[jp] = cvtpk_bf16(v0, v1);
            }
        }

        // accumulator init: gic from global (L1-resident), bhn from LDS
        const float* gt = ws + WS_GIC_F + t * 192;
        f32x4 accR[4], accZ[4], accNi[4], accNh[4];
        #pragma unroll
        for (int a = 0; a < 4; ++a) {
            accR[a]  = *(const f32x4*)(gt + a * 16 + 4 * cp);
            accZ[a]  = *(const f32x4*)(gt + 64 + a * 16 + 4 * cp);
            accNi[a] = *(const f32x4*)(gt + 128 + a * 16 + 4 * cp);
            accNh[a] = *(const f32x4*)(Lf + BHN_OFF / 4 + a * 16 + 4 * cp);
        }

        // input-part MFMAs (K=32), weights from LDS
        #pragma unroll
        for (int a = 0; a < 4; ++a) {
            bf16x8 wr = *(const bf16x8*)(wiS + ((size_t)a * 64 + lane) * 16);
            bf16x8 wz = *(const bf16x8*)(wiS + ((size_t)(4 + a) * 64 + lane) * 16);
            bf16x8 wn = *(const bf16x8*)(wiS + ((size_t)(8 + a) * 64 + lane) * 16);
            accR[a]  = __builtin_amdgcn_mfma_f32_16x16x32_bf16(wr, exf.v, accR[a], 0, 0, 0);
            accZ[a]  = __builtin_amdgcn_mfma_f32_16x16x32_bf16(wz, exf.v, accZ[a], 0, 0, 0);
            accNi[a] = __builtin_amdgcn_mfma_f32_16x16x32_bf16(wn, exf.v, accNi[a], 0, 0, 0);
        }

        // recurrent MFMAs: r,z use hi-only h (error ~1e-4); n uses hi+lo
        if (t > 0) {
            bf16x8 hhi0 = *(const bf16x8*)&Hhi[er * 72 + 8 * cp];
            bf16x8 hhi1 = *(const bf16x8*)&Hhi[er * 72 + 32 + 8 * cp];
            bf16x8 hlo0 = *(const bf16x8*)&Hlo[er * 72 + 8 * cp];
            bf16x8 hlo1 = *(const bf16x8*)&Hlo[er * 72 + 32 + 8 * cp];
            #pragma unroll
            for (int a = 0; a < 4; ++a) {
                bf16x8 wr0 = *(const bf16x8*)(whhS + ((size_t)(a * 2 + 0) * 64 + lane) * 16);
                bf16x8 wr1 = *(const bf16x8*)(whhS + ((size_t)(a * 2 + 1) * 64 + lane) * 16);
                accR[a] = __builtin_amdgcn_mfma_f32_16x16x32_bf16(wr0, hhi0, accR[a], 0, 0, 0);
                accR[a] = __builtin_amdgcn_mfma_f32_16x16x32_bf16(wr1, hhi1, accR[a], 0, 0, 0);
                bf16x8 wz0 = *(const bf16x8*)(whhS + ((size_t)(8 + a * 2 + 0) * 64 + lane) * 16);
                bf16x8 wz1 = *(const bf16x8*)(whhS + ((size_t)(8 + a * 2 + 1) * 64 + lane) * 16);
                accZ[a] = __builtin_amdgcn_mfma_f32_16x16x32_bf16(wz0, hhi0, accZ[a], 0, 0, 0);
                accZ[a] = __builtin_amdgcn_mfma_f32_16x16x32_bf16(wz1, hhi1, accZ[a], 0, 0, 0);
                bf16x8 wn0 = *(const bf16x8*)(whhS + ((size_t)(16 + a * 2 + 0) * 64 + lane) * 16);
                bf16x8 wn1 = *(const bf16x8*)(whhS + ((size_t)(16 + a * 2 + 1) * 64 + lane) * 16);
                accNh[a] = __builtin_amdgcn_mfma_f32_16x16x32_bf16(wn0, hhi0, accNh[a], 0, 0, 0);
                accNh[a] = __builtin_amdgcn_mfma_f32_16x16x32_bf16(wn1, hhi1, accNh[a], 0, 0, 0);
                accNh[a] = __builtin_amdgcn_mfma_f32_16x16x32_bf16(wn0, hlo0, accNh[a], 0, 0, 0);
                accNh[a] = __builtin_amdgcn_mfma_f32_16x16x32_bf16(wn1, hlo1, accNh[a], 0, 0, 0);
            }
        }

        // epilogue: packed-f32 gate math; acc already scaled by log2e (r,z) / 2log2e (n)
        #pragma unroll
        for (int a = 0; a < 4; ++a) {
            uint hiw[2], low[2];
            #pragma unroll
            for (int p = 0; p < 2; ++p) {
                f32x2 aR  = {accR[a][2 * p],  accR[a][2 * p + 1]};
                f32x2 aZ  = {accZ[a][2 * p],  accZ[a][2 * p + 1]};
                f32x2 aNi = {accNi[a][2 * p], accNi[a][2 * p + 1]};
                f32x2 aNh = {accNh[a][2 * p], accNh[a][2 * p + 1]};
                f32x2 eR = {exp2n_(aR.x), exp2n_(aR.y)};
                f32x2 eZ = {exp2n_(aZ.x), exp2n_(aZ.y)};
                f32x2 dR = eR + one2;
                f32x2 dZ = eZ + one2;
                f32x2 r  = {__builtin_amdgcn_rcpf(dR.x), __builtin_amdgcn_rcpf(dR.y)};
                f32x2 z  = {__builtin_amdgcn_rcpf(dZ.x), __builtin_amdgcn_rcpf(dZ.y)};
                f32x2 np = __builtin_elementwise_fma(r, aNh, aNi);     // 2log2e * npre
                f32x2 e2 = {exp2p_(np.x), exp2p_(np.y)};
                f32x2 d2 = e2 + one2;
                f32x2 rc = {__builtin_amdgcn_rcpf(d2.x), __builtin_amdgcn_rcpf(d2.y)};
                f32x2 n  = __builtin_elementwise_fma(rc, negtwo2, one2);  // tanh
                f32x2 hm = hold2[a][p] - n;
                f32x2 h  = __builtin_elementwise_fma(z, hm, n);
                hold2[a][p] = h;
                uint whi = cvtpk_bf16(h.x, h.y);
                f32x2 hh = {__uint_as_float(whi << 16), __uint_as_float(whi & 0xffff0000u)};
                f32x2 lo = h - hh;
                hiw[p] = whi;
                low[p] = cvtpk_bf16(lo.x, lo.y);
            }
            uint2 whiv = {hiw[0], hiw[1]};
            uint2 wlov = {low[0], low[1]};
            *(uint2*)&Hhi[er * 72 + 16 * a + 4 * cp] = whiv;
            *(uint2*)&Hlo[er * 72 + 16 * a + 4 * cp] = wlov;
        }

        xv = xv_next;
    }

    // ---- prediction head ----
    float part = 0.0f;
    #pragma unroll
    for (int a = 0; a < 4; ++a) {
        f32x4 wp = *(const f32x4*)(Wpred + 16 * a + 4 * cp);
        #pragma unroll
        for (int p = 0; p < 2; ++p) {
            part = fmaf(hold2[a][p].x, wp[2 * p], part);
            part = fmaf(hold2[a][p].y, wp[2 * p + 1], part);
        }
    }
    part += __shfl_xor(part, 16);
    part += __shfl_xor(part, 32);
    if (cp == 0) out[eg] = sigm(part + bpred[0]);
}

extern "C" void kernel_launch(void* const* d_in, const int* in_sizes, int n_in,
                              void* d_out, int out_size, void* d_ws, size_t ws_size,
                              hipStream_t stream) {
    const float* x     = (const float*)d_in[0];
    const float* Wloc  = (const float*)d_in[1];
    const float* bloc  = (const float*)d_in[2];
    const float* tt    = (const float*)d_in[3];
    const float* Wih   = (const float*)d_in[4];
    const float* Whh   = (const float*)d_in[5];
    const float* bih   = (const float*)d_in[6];
    const float* bhh   = (const float*)d_in[7];
    const float* Wpred = (const float*)d_in[8];
    const float* bpred = (const float*)d_in[9];
    float* out = (float*)d_out;
    float* ws  = (float*)d_ws;

    (void)hipFuncSetAttribute((const void*)traj_gru_mfma,
                              hipFuncAttributeMaxDynamicSharedMemorySize, LDS_BYTES);

    hipLaunchKernelGGL(traj_gru_pre, dim3(39), dim3(256), 0, stream,
                       Wloc, bloc, tt, Wih, Whh, bih, bhh, ws);
    // 65536 elements / (8 waves * 16 elem) = 512 blocks, 2/CU, all resident
    hipLaunchKernelGGL(traj_gru_mfma, dim3(512), dim3(512), LDS_BYTES, stream,
                       x, ws, Wpred, bpred, out);
}

// Round 8
// 114.187 us; speedup vs baseline: 11.5045x; 1.0440x over previous
//
#include <hip/hip_runtime.h>
#include <hip/hip_bf16.h>

#define TN 24
#define HID 64
#define LOG2E 1.4426950408889634f

// ws layout (bytes):
//   0     : gic [24*192 f32]  (scaled by log2e / 2log2e)   (18432)
//   18432 : bhn [64 f32]      (scaled by 2log2e)           (256)
//   18688 : wlc [96 f32]      (unscaled)                   (384)
//   19072 : frags [36][64] x 16B bf16x8 (scaled)           (36864)
#define WS_GIC_F   0
#define WS_BHN_F   4608
#define WS_WLC_F   4672
#define WS_FRAG_B  19072

// dynamic LDS layout (bytes), total 111232:
#define HHI_OFF  0        // ushort [8 waves][32 elem][72]  36864
#define HLO_OFF  36864    // ushort [8 waves][32 elem][72]  36864
#define WHH_OFF  73728    // 24 frags x 64 lanes x 16B      24576
#define WI_OFF   98304    // 12 frags x 64 lanes x 16B      12288
#define BHN_OFF  110592   // 64 f32
#define WLC_OFF  110848   // 96 f32
#define LDS_BYTES 111232

typedef __attribute__((ext_vector_type(8))) short bf16x8;
typedef __attribute__((ext_vector_type(4))) float f32x4;
typedef __attribute__((ext_vector_type(2))) float f32x2;

__device__ __forceinline__ ushort bf16rn(float f) {
    uint x = __float_as_uint(f);
    return (ushort)((x + 0x7fffu + ((x >> 16) & 1u)) >> 16);
}
__device__ __forceinline__ uint cvtpk_bf16(float lo, float hi) {
    uint r;
    asm("v_cvt_pk_bf16_f32 %0, %1, %2" : "=v"(r) : "v"(lo), "v"(hi));
    return r;
}
__device__ __forceinline__ float exp2p_(float x) {   // 2^x
    float r; asm("v_exp_f32 %0, %1" : "=v"(r) : "v"(x)); return r;
}
__device__ __forceinline__ float exp2n_(float x) {   // 2^-x (free neg modifier)
    float r; asm("v_exp_f32 %0, -%1" : "=v"(r) : "v"(x)); return r;
}
__device__ __forceinline__ float sigm(float v) {
    return __builtin_amdgcn_rcpf(1.0f + __expf(-v));
}

// ---------------- pre-kernel: build scaled gic + bf16 fragment tables in ws ----------------
extern "C" __global__ void __launch_bounds__(256)
traj_gru_pre(const float* __restrict__ Wloc, const float* __restrict__ bloc,
             const float* __restrict__ tt, const float* __restrict__ Wih,
             const float* __restrict__ Whh, const float* __restrict__ bih,
             const float* __restrict__ bhh, float* __restrict__ ws)
{
    const int b = blockIdx.x, tid = threadIdx.x;
    if (b < 36) {
        if (tid < 64) {
            const int er = tid & 15, cp = tid >> 4;
            const float* src;
            float s;
            if (b < 8) {            // wih R (0-3), Z (4-7): scale log2e
                int g = b >> 2, a = b & 3;
                src = Wih + (size_t)(g * 64 + a * 16 + er) * 64 + 8 * cp;
                s = LOG2E;
            } else if (b < 32) {    // whh frags: r,z -> log2e; n -> 2log2e
                int t = b - 8, g = t >> 3, r = t & 7, a = r >> 1, f = r & 1;
                src = Whh + (size_t)(g * 64 + a * 16 + er) * 64 + 32 * f + 8 * cp;
                s = (g == 2) ? 2.0f * LOG2E : LOG2E;
            } else {                // wih n-gate: 2log2e
                int a = b - 32;
                src = Wih + (size_t)(128 + a * 16 + er) * 64 + 8 * cp;
                s = 2.0f * LOG2E;
            }
            union { ushort u[8]; bf16x8 v; } fr;
            #pragma unroll
            for (int j = 0; j < 8; ++j) fr.u[j] = bf16rn(s * src[j]);
            *(bf16x8*)((char*)ws + WS_FRAG_B + ((size_t)b * 64 + tid) * 16) = fr.v;
        }
    } else if (b < 38) {
        const int base = (b - 36) * 2304;
        for (int i = tid; i < 2304; i += 256) {
            int idx = base + i, t = idx / 192, g = idx % 192;
            float acc = bih[g] + (g < 128 ? bhh[g] : 0.0f);
            const float* ttr = tt + t * 32;
            const float* wr  = Wih + g * 64 + 32;
            #pragma unroll
            for (int k = 0; k < 32; ++k) {
                float e = ttr[k];
                e = fmaxf(e, 0.2f * e);
                acc = fmaf(wr[k], e, acc);
            }
            ws[WS_GIC_F + idx] = acc * (g < 128 ? LOG2E : 2.0f * LOG2E);
        }
    } else {
        if (tid < 64) ws[WS_BHN_F + tid] = 2.0f * LOG2E * bhh[128 + tid];
        if (tid < 96) ws[WS_WLC_F + tid] = (tid < 64) ? Wloc[tid] : bloc[tid - 64];
    }
}

// ---------------- main kernel: each wave owns 32 elements (two B-frags) ----------------
extern "C" __global__ void __launch_bounds__(512, 2)
traj_gru_mfma(const float* __restrict__ x, const float* __restrict__ ws,
              const float* __restrict__ Wpred, const float* __restrict__ bpred,
              float* __restrict__ out)
{
    extern __shared__ __align__(16) char L[];
    float*  Lf   = (float*)L;
    char*   whhS = L + WHH_OFF;
    char*   wiS  = L + WI_OFF;

    const int tid  = threadIdx.x;
    const int lane = tid & 63;
    const int wid  = tid >> 6;       // wave 0..7
    const int er   = lane & 15;      // A-row / B-col / D-col index
    const int cp   = lane >> 4;      // k-block / D-row-block

    // ---- stage all 36 weight frags ws -> LDS (coalesced 16B chunks) ----
    const char* fb = (const char*)ws + WS_FRAG_B;
    for (int i = tid; i < 36 * 64; i += 512) {
        int f = i >> 6, l = i & 63;
        bf16x8 v = *(const bf16x8*)(fb + (size_t)i * 16);
        char* dst;
        if (f < 8)       dst = wiS  + ((size_t)f * 64 + l) * 16;        // R,Z input frags
        else if (f < 32) dst = whhS + ((size_t)(f - 8) * 64 + l) * 16;  // recurrent frags
        else             dst = wiS  + ((size_t)(f - 24) * 64 + l) * 16; // n input frags -> 8..11
        *(bf16x8*)dst = v;
    }
    if (tid < 64) Lf[BHN_OFF / 4 + tid] = ws[WS_BHN_F + tid];
    if (tid < 96) Lf[WLC_OFF / 4 + tid] = ws[WS_WLC_F + tid];
    __syncthreads();   // the only barrier

    const f32x2* wlc2 = (const f32x2*)(Lf + WLC_OFF / 4);
    ushort* Hhi = (ushort*)(L + HHI_OFF) + (size_t)(wid * 32) * 72;
    ushort* Hlo = (ushort*)(L + HLO_OFF) + (size_t)(wid * 32) * 72;

    // bhn accumulator-init: loop-invariant -> registers
    f32x4 bhnR[4];
    #pragma unroll
    for (int a = 0; a < 4; ++a)
        bhnR[a] = *(const f32x4*)(Lf + BHN_OFF / 4 + a * 16 + 4 * cp);

    // ---- wave's elements: ego + er (bf0), ego + 16 + er (bf1) ----
    const int ego = (blockIdx.x * 8 + wid) * 32;
    const float* xr0 = x + (size_t)(ego + er) * (TN * 2);
    const float* xr1 = x + (size_t)(ego + 16 + er) * (TN * 2);

    f32x2 hold2[2][4][2];
    #pragma unroll
    for (int bf = 0; bf < 2; ++bf)
        #pragma unroll
        for (int a = 0; a < 4; ++a)
            #pragma unroll
            for (int p = 0; p < 2; ++p) hold2[bf][a][p] = (f32x2){0.0f, 0.0f};

    const f32x2 one2    = {1.0f, 1.0f};
    const f32x2 negtwo2 = {-2.0f, -2.0f};

    float2 xv0 = *(const float2*)(xr0);
    float2 xv1 = *(const float2*)(xr1);

    #pragma unroll 1
    for (int t = 0; t < TN; ++t) {
        const int tn = (t + 1 < TN) ? t + 1 : TN - 1;
        float2 xv0n = *(const float2*)(xr0 + tn * 2);
        float2 xv1n = *(const float2*)(xr1 + tn * 2);

        // ex B-frags for both halves: ex[k = 8cp+j][elem]
        union { uint u[4]; bf16x8 v; } exf0, exf1;
        {
            f32x2 xx0 = {xv0.x, xv0.x}, yy0 = {xv0.y, xv0.y};
            f32x2 xx1 = {xv1.x, xv1.x}, yy1 = {xv1.y, xv1.y};
            #pragma unroll
            for (int jp = 0; jp < 4; ++jp) {
                int kp = 4 * cp + jp;   // k pair index
                f32x2 w1 = wlc2[kp], w2 = wlc2[16 + kp], bl = wlc2[32 + kp];
                f32x2 v0 = __builtin_elementwise_fma(xx0, w1,
                           __builtin_elementwise_fma(yy0, w2, bl));
                f32x2 v1 = __builtin_elementwise_fma(xx1, w1,
                           __builtin_elementwise_fma(yy1, w2, bl));
                exf0.u[jp] = cvtpk_bf16(fmaxf(v0.x, 0.2f * v0.x), fmaxf(v0.y, 0.2f * v0.y));
                exf1.u[jp] = cvtpk_bf16(fmaxf(v1.x, 0.2f * v1.x), fmaxf(v1.y, 0.2f * v1.y));
            }
        }

        // shared accumulator init from gic (element-independent)
        const float* gt = ws + WS_GIC_F + t * 192;
        f32x4 gR[4], gZ[4], gNi[4];
        #pragma unroll
        for (int a = 0; a < 4; ++a) {
            gR[a]  = *(const f32x4*)(gt + a * 16 + 4 * cp);
            gZ[a]  = *(const f32x4*)(gt + 64 + a * 16 + 4 * cp);
            gNi[a] = *(const f32x4*)(gt + 128 + a * 16 + 4 * cp);
        }

        f32x4 accR[2][4], accZ[2][4], accNi[2][4], accNh[2][4];

        // input-part MFMAs (K=32): each weight read feeds both halves
        #pragma unroll
        for (int a = 0; a < 4; ++a) {
            bf16x8 wr = *(const bf16x8*)(wiS + ((size_t)a * 64 + lane) * 16);
            bf16x8 wz = *(const bf16x8*)(wiS + ((size_t)(4 + a) * 64 + lane) * 16);
            bf16x8 wn = *(const bf16x8*)(wiS + ((size_t)(8 + a) * 64 + lane) * 16);
            accR[0][a]  = __builtin_amdgcn_mfma_f32_16x16x32_bf16(wr, exf0.v, gR[a], 0, 0, 0);
            accR[1][a]  = __builtin_amdgcn_mfma_f32_16x16x32_bf16(wr, exf1.v, gR[a], 0, 0, 0);
            accZ[0][a]  = __builtin_amdgcn_mfma_f32_16x16x32_bf16(wz, exf0.v, gZ[a], 0, 0, 0);
            accZ[1][a]  = __builtin_amdgcn_mfma_f32_16x16x32_bf16(wz, exf1.v, gZ[a], 0, 0, 0);
            accNi[0][a] = __builtin_amdgcn_mfma_f32_16x16x32_bf16(wn, exf0.v, gNi[a], 0, 0, 0);
            accNi[1][a] = __builtin_amdgcn_mfma_f32_16x16x32_bf16(wn, exf1.v, gNi[a], 0, 0, 0);
        }

        // recurrent MFMAs: r,z hi-only; n hi+lo. Weight reads shared across halves.
        if (t > 0) {
            bf16x8 hh0[2], hh1[2], hl0[2], hl1[2];
            #pragma unroll
            for (int bf = 0; bf < 2; ++bf) {
                const int row = (bf * 16 + er) * 72;
                hh0[bf] = *(const bf16x8*)&Hhi[row + 8 * cp];
                hh1[bf] = *(const bf16x8*)&Hhi[row + 32 + 8 * cp];
                hl0[bf] = *(const bf16x8*)&Hlo[row + 8 * cp];
                hl1[bf] = *(const bf16x8*)&Hlo[row + 32 + 8 * cp];
            }
            #pragma unroll
            for (int a = 0; a < 4; ++a) {
                bf16x8 wr0 = *(const bf16x8*)(whhS + ((size_t)(a * 2 + 0) * 64 + lane) * 16);
                bf16x8 wr1 = *(const bf16x8*)(whhS + ((size_t)(a * 2 + 1) * 64 + lane) * 16);
                accR[0][a] = __builtin_amdgcn_mfma_f32_16x16x32_bf16(wr0, hh0[0], accR[0][a], 0, 0, 0);
                accR[0][a] = __builtin_amdgcn_mfma_f32_16x16x32_bf16(wr1, hh1[0], accR[0][a], 0, 0, 0);
                accR[1][a] = __builtin_amdgcn_mfma_f32_16x16x32_bf16(wr0, hh0[1], accR[1][a], 0, 0, 0);
                accR[1][a] = __builtin_amdgcn_mfma_f32_16x16x32_bf16(wr1, hh1[1], accR[1][a], 0, 0, 0);
                bf16x8 wz0 = *(const bf16x8*)(whhS + ((size_t)(8 + a * 2 + 0) * 64 + lane) * 16);
                bf16x8 wz1 = *(const bf16x8*)(whhS + ((size_t)(8 + a * 2 + 1) * 64 + lane) * 16);
                accZ[0][a] = __builtin_amdgcn_mfma_f32_16x16x32_bf16(wz0, hh0[0], accZ[0][a], 0, 0, 0);
                accZ[0][a] = __builtin_amdgcn_mfma_f32_16x16x32_bf16(wz1, hh1[0], accZ[0][a], 0, 0, 0);
                accZ[1][a] = __builtin_amdgcn_mfma_f32_16x16x32_bf16(wz0, hh0[1], accZ[1][a], 0, 0, 0);
                accZ[1][a] = __builtin_amdgcn_mfma_f32_16x16x32_bf16(wz1, hh1[1], accZ[1][a], 0, 0, 0);
                bf16x8 wn0 = *(const bf16x8*)(whhS + ((size_t)(16 + a * 2 + 0) * 64 + lane) * 16);
                bf16x8 wn1 = *(const bf16x8*)(whhS + ((size_t)(16 + a * 2 + 1) * 64 + lane) * 16);
                accNh[0][a] = __builtin_amdgcn_mfma_f32_16x16x32_bf16(wn0, hh0[0], bhnR[a], 0, 0, 0);
                accNh[0][a] = __builtin_amdgcn_mfma_f32_16x16x32_bf16(wn1, hh1[0], accNh[0][a], 0, 0, 0);
                accNh[0][a] = __builtin_amdgcn_mfma_f32_16x16x32_bf16(wn0, hl0[0], accNh[0][a], 0, 0, 0);
                accNh[0][a] = __builtin_amdgcn_mfma_f32_16x16x32_bf16(wn1, hl1[0], accNh[0][a], 0, 0, 0);
                accNh[1][a] = __builtin_amdgcn_mfma_f32_16x16x32_bf16(wn0, hh0[1], bhnR[a], 0, 0, 0);
                accNh[1][a] = __builtin_amdgcn_mfma_f32_16x16x32_bf16(wn1, hh1[1], accNh[1][a], 0, 0, 0);
                accNh[1][a] = __builtin_amdgcn_mfma_f32_16x16x32_bf16(wn0, hl0[1], accNh[1][a], 0, 0, 0);
                accNh[1][a] = __builtin_amdgcn_mfma_f32_16x16x32_bf16(wn1, hl1[1], accNh[1][a], 0, 0, 0);
            }
        } else {
            #pragma unroll
            for (int bf = 0; bf < 2; ++bf)
                #pragma unroll
                for (int a = 0; a < 4; ++a) accNh[bf][a] = bhnR[a];
        }

        // epilogue: packed-f32 gate math; acc pre-scaled by log2e (r,z) / 2log2e (n)
        #pragma unroll
        for (int bf = 0; bf < 2; ++bf) {
            const int row = (bf * 16 + er) * 72;
            #pragma unroll
            for (int a = 0; a < 4; ++a) {
                uint hiw[2], low[2];
                #pragma unroll
                for (int p = 0; p < 2; ++p) {
                    f32x2 aR  = {accR[bf][a][2 * p],  accR[bf][a][2 * p + 1]};
                    f32x2 aZ  = {accZ[bf][a][2 * p],  accZ[bf][a][2 * p + 1]};
                    f32x2 aNi = {accNi[bf][a][2 * p], accNi[bf][a][2 * p + 1]};
                    f32x2 aNh = {accNh[bf][a][2 * p], accNh[bf][a][2 * p + 1]};
                    f32x2 eR = {exp2n_(aR.x), exp2n_(aR.y)};
                    f32x2 eZ = {exp2n_(aZ.x), exp2n_(aZ.y)};
                    f32x2 dR = eR + one2;
                    f32x2 dZ = eZ + one2;
                    f32x2 r  = {__builtin_amdgcn_rcpf(dR.x), __builtin_amdgcn_rcpf(dR.y)};
                    f32x2 z  = {__builtin_amdgcn_rcpf(dZ.x), __builtin_amdgcn_rcpf(dZ.y)};
                    f32x2 np = __builtin_elementwise_fma(r, aNh, aNi);     // 2log2e * npre
                    f32x2 e2 = {exp2p_(np.x), exp2p_(np.y)};
                    f32x2 d2 = e2 + one2;
                    f32x2 rc = {__builtin_amdgcn_rcpf(d2.x), __builtin_amdgcn_rcpf(d2.y)};
                    f32x2 n  = __builtin_elementwise_fma(rc, negtwo2, one2);  // tanh
                    f32x2 hm = hold2[bf][a][p] - n;
                    f32x2 h  = __builtin_elementwise_fma(z, hm, n);
                    hold2[bf][a][p] = h;
                    uint whi = cvtpk_bf16(h.x, h.y);
                    f32x2 hh = {__uint_as_float(whi << 16), __uint_as_float(whi & 0xffff0000u)};
                    f32x2 lo = h - hh;
                    hiw[p] = whi;
                    low[p] = cvtpk_bf16(lo.x, lo.y);
                }
                uint2 whiv = {hiw[0], hiw[1]};
                uint2 wlov = {low[0], low[1]};
                *(uint2*)&Hhi[row + 16 * a + 4 * cp] = whiv;
                *(uint2*)&Hlo[row + 16 * a + 4 * cp] = wlov;
            }
        }

        xv0 = xv0n;
        xv1 = xv1n;
    }

    // ---- prediction head (both halves) ----
    float p0 = 0.0f, p1 = 0.0f;
    #pragma unroll
    for (int a = 0; a < 4; ++a) {
        f32x4 wp = *(const f32x4*)(Wpred + 16 * a + 4 * cp);
        #pragma unroll
        for (int p = 0; p < 2; ++p) {
            p0 = fmaf(hold2[0][a][p].x, wp[2 * p], p0);
            p0 = fmaf(hold2[0][a][p].y, wp[2 * p + 1], p0);
            p1 = fmaf(hold2[1][a][p].x, wp[2 * p], p1);
            p1 = fmaf(hold2[1][a][p].y, wp[2 * p + 1], p1);
        }
    }
    p0 += __shfl_xor(p0, 16);  p0 += __shfl_xor(p0, 32);
    p1 += __shfl_xor(p1, 16);  p1 += __shfl_xor(p1, 32);
    if (cp == 0) {
        float bp = bpred[0];
        out[ego + er]      = sigm(p0 + bp);
        out[ego + 16 + er] = sigm(p1 + bp);
    }
}

extern "C" void kernel_launch(void* const* d_in, const int* in_sizes, int n_in,
                              void* d_out, int out_size, void* d_ws, size_t ws_size,
                              hipStream_t stream) {
    const float* x     = (const float*)d_in[0];
    const float* Wloc  = (const float*)d_in[1];
    const float* bloc  = (const float*)d_in[2];
    const float* tt    = (const float*)d_in[3];
    const float* Wih   = (const float*)d_in[4];
    const float* Whh   = (const float*)d_in[5];
    const float* bih   = (const float*)d_in[6];
    const float* bhh   = (const float*)d_in[7];
    const float* Wpred = (const float*)d_in[8];
    const float* bpred = (const float*)d_in[9];
    float* out = (float*)d_out;
    float* ws  = (float*)d_ws;

    (void)hipFuncSetAttribute((const void*)traj_gru_mfma,
                              hipFuncAttributeMaxDynamicSharedMemorySize, LDS_BYTES);

    hipLaunchKernelGGL(traj_gru_pre, dim3(39), dim3(256), 0, stream,
                       Wloc, bloc, tt, Wih, Whh, bih, bhh, ws);
    // 65536 elements / (8 waves * 32 elem) = 256 blocks of 512 threads = 1/CU
    hipLaunchKernelGGL(traj_gru_mfma, dim3(256), dim3(512), LDS_BYTES, stream,
                       x, ws, Wpred, bpred, out);
}